// Round 8
// baseline (162.049 us; speedup 1.0000x reference)
//
#include <hip/hip_runtime.h>

#define WW 1280
#define HH 720
#define NB 8
#define NPIX (HH * WW)            // 921600
#define TOTAL (NB * NPIX)         // 7372800

#define FMAX 4.0f                 // |flow| < 4 -> inlier (corners within +/-4)
#define RHALO 4
#define TH 16                     // 720 = 45*16
#define TW 64                     // 1280 = 20*64
#define TPIX (TH * TW)            // 1024 -> 16KB LDS (4 arrays)
#define TILES_X (WW / TW)         // 20
#define TILES_Y (HH / TH)         // 45
#define TPB (TILES_X * TILES_Y)   // 900
#define NT (NB * TPB)             // 7200 (divisible by 8)
#define WH (TH + 2 * RHALO)       // 24
#define WWIN (TW + 2 * RHALO)     // 72
#define WPOS (WH * WWIN)          // 1728 scalar window positions
#define TB 512                    // threads per block
#define NITER 4                   // ceil(WPOS/TB)
#define CAPB 4096                 // per-batch outlier capacity (expect ~120)

// ---------------------------------------------------------------------------
// K1: build per-batch outlier lists (valid target but |fx|>=4 or |fy|>=4).
// Entry = {pixel, fx_bits, fy_bits, depth_bits} so K2 never reloads them.
// ---------------------------------------------------------------------------
__global__ void k1_outliers(const float* __restrict__ flow,
                            const float* __restrict__ depth,
                            int* __restrict__ nOut, int4* __restrict__ lists) {
    int i = blockIdx.x * blockDim.x + threadIdx.x;      // one float4 group
    int p4 = i * 4;
    int b = p4 / NPIX;
    int p = p4 - b * NPIX;
    int y = p / WW;
    int x0 = p - y * WW;
    const float* fb = flow + (size_t)b * 2 * NPIX;
    float4 fx4 = *(const float4*)&fb[p];
    float4 fy4 = *(const float4*)&fb[p + NPIX];
    float fxs[4] = {fx4.x, fx4.y, fx4.z, fx4.w};
    float fys[4] = {fy4.x, fy4.y, fy4.z, fy4.w};
#pragma unroll
    for (int j = 0; j < 4; ++j) {
        float fx = fxs[j], fy = fys[j];
        if (fabsf(fx) < FMAX && fabsf(fy) < FMAX) continue;          // inlier
        float x2 = (float)(x0 + j) + fx, y2 = (float)y + fy;
        if (!(x2 >= 0.f && y2 >= 0.f && x2 <= (float)(WW - 1) && y2 <= (float)(HH - 1)))
            continue;                                                 // invalid
        float d = depth[(size_t)b * NPIX + p + j];
        int pos = atomicAdd(&nOut[b], 1);
        if (pos < CAPB)
            lists[b * CAPB + pos] =
                make_int4(p + j, __float_as_int(fx), __float_as_int(fy), __float_as_int(d));
    }
}

// ---------------------------------------------------------------------------
// K2: per-tile gather, 512 threads/block (4 serial iters/thread), scalar
// 1px/lane. Phase A: pre-issue ALL window loads to regs, then decode +
// LDS atomicMin. Phase B: replay from regs with BATCHED unconditional gate
// reads (one lgkmcnt wait for 4 reads) then masked adds. Outliers merged
// from per-batch lists. Divide + store owned tile.
// Packed: bit31 = valid; bits13..9 = lyT+8; bits8..2 = lxL+8;
// bit1 = xR clamped; bit0 = yB clamped.
// ---------------------------------------------------------------------------
__global__ void __launch_bounds__(TB, 8)
k2_gather(const float* __restrict__ flow, const float* __restrict__ depth,
          const int* __restrict__ nOut, const int4* __restrict__ lists,
          float* __restrict__ out) {
    __shared__ int   mind_t[TPIX];
    __shared__ float sx_t[TPIX];
    __shared__ float sy_t[TPIX];
    __shared__ float cn_t[TPIX];

    int bid = blockIdx.x;
    { const int c = NT >> 3; bid = (bid & 7) * c + (bid >> 3); }  // XCD swizzle
    const int b   = bid / TPB;
    const int tt  = bid - b * TPB;
    const int tty = tt / TILES_X;
    const int ty0 = tty * TH;
    const int tx0 = (tt - tty * TILES_X) * TW;
    const int tid = threadIdx.x;
    const float* flowb  = flow  + (size_t)b * 2 * NPIX;
    const float* depthb = depth + (size_t)b * NPIX;

    {   // vectorized init: one float2 per array per thread (TPIX == TB*2)
        int k2 = tid * 2;
        const int IB = __float_as_int(1e30f);
        *(int2*)&mind_t[k2] = make_int2(IB, IB);
        float2 z = make_float2(0.f, 0.f);
        *(float2*)&sx_t[k2] = z;
        *(float2*)&sy_t[k2] = z;
        *(float2*)&cn_t[k2] = z;
    }
    __syncthreads();

    // ---- pre-issue all window loads (clamped addresses, masked later) ----
    float fxA[NITER], fyA[NITER], dA[NITER];
#pragma unroll
    for (int it = 0; it < NITER; ++it) {
        int s  = tid + it * TB;
        int wy = s / WWIN;
        int wx = s - wy * WWIN;
        int gy = ty0 - RHALO + wy;
        int gx = tx0 - RHALO + wx;
        bool ok = (s < WPOS) && ((unsigned)gy < HH) && ((unsigned)gx < WW);
        int p = ok ? gy * WW + gx : 0;
        fxA[it] = flowb[p];
        fyA[it] = flowb[p + NPIX];
        dA[it]  = depthb[p];
    }

    // ---- phase A: decode + LDS atomicMin; capture packed geometry ----
    unsigned pkA[NITER];
#pragma unroll
    for (int it = 0; it < NITER; ++it) {
        pkA[it] = 0u;
        int s  = tid + it * TB;
        int wy = s / WWIN;
        int wx = s - wy * WWIN;
        int gy = ty0 - RHALO + wy;
        int gx = tx0 - RHALO + wx;
        if (s >= WPOS || (unsigned)gy >= HH || (unsigned)gx >= WW) continue;
        float fx = fxA[it], fy = fyA[it];
        if (!(fabsf(fx) < FMAX && fabsf(fy) < FMAX)) continue;
        float x2 = (float)gx + fx, y2 = (float)gy + fy;
        if (!(x2 >= 0.f && y2 >= 0.f && x2 <= (float)(WW - 1) && y2 <= (float)(HH - 1)))
            continue;
        int xL = (int)floorf(x2), yT = (int)floorf(y2);   // >=0 given validity
        int xR = min(xL + 1, WW - 1), yB = min(yT + 1, HH - 1);
        int cR = (xR == xL), cB = (yB == yT);
        int lxL = xL - tx0, lyT = yT - ty0;
        int lxR = lxL + (cR ^ 1), lyB = lyT + (cB ^ 1);
        pkA[it] = 0x80000000u | (unsigned)((lyT + 8) << 9) |
                  (unsigned)((lxL + 8) << 2) | (unsigned)(cR << 1) | (unsigned)cB;
        int db = __float_as_int(dA[it]);
        if ((unsigned)lyT < TH) {
            if ((unsigned)lxL < TW) atomicMin(&mind_t[lyT * TW + lxL], db);
            if ((unsigned)lxR < TW) atomicMin(&mind_t[lyT * TW + lxR], db);
        }
        if ((unsigned)lyB < TH) {
            if ((unsigned)lxL < TW) atomicMin(&mind_t[lyB * TW + lxL], db);
            if ((unsigned)lxR < TW) atomicMin(&mind_t[lyB * TW + lxR], db);
        }
    }
    // ---- outlier mins (per-batch list, self-contained entries) ----
    const int nb = min(nOut[b], CAPB);
    for (int j = tid; j < nb; j += TB) {
        int4 e = lists[b * CAPB + j];
        float fx = __int_as_float(e.y), fy = __int_as_float(e.z);
        int y = e.x / WW, x = e.x - y * WW;
        float x2 = (float)x + fx, y2 = (float)y + fy;
        int xL = min(max((int)floorf(x2), 0), WW - 1);
        int yT = min(max((int)floorf(y2), 0), HH - 1);
        int xR = min(xL + 1, WW - 1), yB = min(yT + 1, HH - 1);
        int lxL = xL - tx0, lxR = xR - tx0, lyT = yT - ty0, lyB = yB - ty0;
        if ((unsigned)lyT < TH) {
            if ((unsigned)lxL < TW) atomicMin(&mind_t[lyT * TW + lxL], e.w);
            if ((unsigned)lxR < TW) atomicMin(&mind_t[lyT * TW + lxR], e.w);
        }
        if ((unsigned)lyB < TH) {
            if ((unsigned)lxL < TW) atomicMin(&mind_t[lyB * TW + lxL], e.w);
            if ((unsigned)lxR < TW) atomicMin(&mind_t[lyB * TW + lxR], e.w);
        }
    }
    __syncthreads();

    // ---- phase B: replay from regs; BATCHED gate reads, masked adds ----
#pragma unroll
    for (int it = 0; it < NITER; ++it) {
        unsigned pk = pkA[it];
        bool va = (pk >> 31) != 0u;
        int lxL = (int)((pk >> 2) & 0x7Fu) - 8;
        int lyT = (int)((pk >> 9) & 0x1Fu) - 8;
        int lxR = lxL + 1 - (int)((pk >> 1) & 1u);
        int lyB = lyT + 1 - (int)(pk & 1u);
        bool o0 = va && (unsigned)lyT < TH && (unsigned)lxL < TW;
        bool o1 = va && (unsigned)lyT < TH && (unsigned)lxR < TW;
        bool o2 = va && (unsigned)lyB < TH && (unsigned)lxL < TW;
        bool o3 = va && (unsigned)lyB < TH && (unsigned)lxR < TW;
        int i0 = o0 ? lyT * TW + lxL : 0;
        int i1 = o1 ? lyT * TW + lxR : 0;
        int i2 = o2 ? lyB * TW + lxL : 0;
        int i3 = o3 ? lyB * TW + lxR : 0;
        int v0 = mind_t[i0];          // 4 independent reads -> one wait
        int v1 = mind_t[i1];
        int v2 = mind_t[i2];
        int v3 = mind_t[i3];
        float fx = fxA[it], fy = fyA[it];
        int db = __float_as_int(dA[it]);
        if (o0 && v0 == db) {
            atomicAdd(&sx_t[i0], -fx); atomicAdd(&sy_t[i0], -fy); atomicAdd(&cn_t[i0], 1.f);
        }
        if (o1 && v1 == db) {
            atomicAdd(&sx_t[i1], -fx); atomicAdd(&sy_t[i1], -fy); atomicAdd(&cn_t[i1], 1.f);
        }
        if (o2 && v2 == db) {
            atomicAdd(&sx_t[i2], -fx); atomicAdd(&sy_t[i2], -fy); atomicAdd(&cn_t[i2], 1.f);
        }
        if (o3 && v3 == db) {
            atomicAdd(&sx_t[i3], -fx); atomicAdd(&sy_t[i3], -fy); atomicAdd(&cn_t[i3], 1.f);
        }
    }
    // ---- outlier adds ----
    for (int j = tid; j < nb; j += TB) {
        int4 e = lists[b * CAPB + j];
        float fx = __int_as_float(e.y), fy = __int_as_float(e.z);
        int y = e.x / WW, x = e.x - y * WW;
        float x2 = (float)x + fx, y2 = (float)y + fy;
        int xL = min(max((int)floorf(x2), 0), WW - 1);
        int yT = min(max((int)floorf(y2), 0), HH - 1);
        int xR = min(xL + 1, WW - 1), yB = min(yT + 1, HH - 1);
        int lxL = xL - tx0, lxR = xR - tx0, lyT = yT - ty0, lyB = yB - ty0;
        int ls[4] = {
            ((unsigned)lyT < TH && (unsigned)lxL < TW) ? lyT * TW + lxL : -1,
            ((unsigned)lyT < TH && (unsigned)lxR < TW) ? lyT * TW + lxR : -1,
            ((unsigned)lyB < TH && (unsigned)lxL < TW) ? lyB * TW + lxL : -1,
            ((unsigned)lyB < TH && (unsigned)lxR < TW) ? lyB * TW + lxR : -1 };
#pragma unroll
        for (int c = 0; c < 4; ++c) {
            int l = ls[c];
            if (l >= 0 && mind_t[l] == e.w) {
                atomicAdd(&sx_t[l], -fx);
                atomicAdd(&sy_t[l], -fy);
                atomicAdd(&cn_t[l], 1.0f);
            }
        }
    }
    __syncthreads();

    // ---- epilogue: divide + float2 store of the owned tile ----
    {
        int k2 = tid * 2;
        int ly = k2 >> 6;          // /TW
        int lx = k2 & 63;
        float2 s2 = *(float2*)&sx_t[k2];
        float2 t2 = *(float2*)&sy_t[k2];
        float2 c2 = *(float2*)&cn_t[k2];
        float2 ox, oy;
        ox.x = (c2.x > 0.f) ? s2.x / c2.x : 0.f;  oy.x = (c2.x > 0.f) ? t2.x / c2.x : 0.f;
        ox.y = (c2.y > 0.f) ? s2.y / c2.y : 0.f;  oy.y = (c2.y > 0.f) ? t2.y / c2.y : 0.f;
        size_t o = (size_t)b * 2 * NPIX + (size_t)(ty0 + ly) * WW + (tx0 + lx);
        *(float2*)&out[o]        = ox;
        *(float2*)&out[o + NPIX] = oy;
    }
}

extern "C" void kernel_launch(void* const* d_in, const int* in_sizes, int n_in,
                              void* d_out, int out_size, void* d_ws, size_t ws_size,
                              hipStream_t stream) {
    const float* flow  = (const float*)d_in[0];
    const float* depth = (const float*)d_in[1];
    float* out = (float*)d_out;

    int*  nOut  = (int*)d_ws;                 // 16 ints (first NB used)
    int4* lists = (int4*)((char*)d_ws + 64);  // NB * CAPB entries

    hipMemsetAsync(nOut, 0, 64, stream);
    k1_outliers<<<TOTAL / 4 / 256, 256, 0, stream>>>(flow, depth, nOut, lists);
    k2_gather  <<<NT, TB, 0, stream>>>(flow, depth, nOut, lists, out);
}

// Round 9
// 159.460 us; speedup vs baseline: 1.0162x; 1.0162x over previous
//
#include <hip/hip_runtime.h>

#define WW 1280
#define HH 720
#define NB 8
#define NPIX (HH * WW)            // 921600
#define TOTAL (NB * NPIX)         // 7372800

#define FMAX 4.0f                 // |flow| < 4 -> inlier (corners within +/-4)
#define RHALO 4
#define TH 16                     // 720 = 45*16
#define TW 64                     // 1280 = 20*64
#define TPIX (TH * TW)            // 1024 -> 16KB LDS (4 arrays)
#define TILES_X (WW / TW)         // 20
#define TILES_Y (HH / TH)         // 45
#define TPB (TILES_X * TILES_Y)   // 900
#define NT (NB * TPB)             // 7200 (divisible by 8)
#define WH (TH + 2 * RHALO)       // 24
#define WWIN (TW + 2 * RHALO)     // 72
#define WPOS (WH * WWIN)          // 1728 scalar window positions
#define TB 256                    // threads per block
#define NITER 7                   // ceil(WPOS/TB)
#define CAPB 4096                 // per-batch outlier capacity (expect ~120)

// ---------------------------------------------------------------------------
// K1: build per-batch outlier lists (valid target but |fx|>=4 or |fy|>=4).
// Entry = {pixel, fx_bits, fy_bits, depth_bits} so K2 never reloads them.
// ---------------------------------------------------------------------------
__global__ void k1_outliers(const float* __restrict__ flow,
                            const float* __restrict__ depth,
                            int* __restrict__ nOut, int4* __restrict__ lists) {
    int i = blockIdx.x * blockDim.x + threadIdx.x;      // one float4 group
    int p4 = i * 4;
    int b = p4 / NPIX;
    int p = p4 - b * NPIX;
    int y = p / WW;
    int x0 = p - y * WW;
    const float* fb = flow + (size_t)b * 2 * NPIX;
    float4 fx4 = *(const float4*)&fb[p];
    float4 fy4 = *(const float4*)&fb[p + NPIX];
    float fxs[4] = {fx4.x, fx4.y, fx4.z, fx4.w};
    float fys[4] = {fy4.x, fy4.y, fy4.z, fy4.w};
#pragma unroll
    for (int j = 0; j < 4; ++j) {
        float fx = fxs[j], fy = fys[j];
        if (fabsf(fx) < FMAX && fabsf(fy) < FMAX) continue;          // inlier
        float x2 = (float)(x0 + j) + fx, y2 = (float)y + fy;
        if (!(x2 >= 0.f && y2 >= 0.f && x2 <= (float)(WW - 1) && y2 <= (float)(HH - 1)))
            continue;                                                 // invalid
        float d = depth[(size_t)b * NPIX + p + j];
        int pos = atomicAdd(&nOut[b], 1);
        if (pos < CAPB)
            lists[b * CAPB + pos] =
                make_int4(p + j, __float_as_int(fx), __float_as_int(fy), __float_as_int(d));
    }
}

// ---------------------------------------------------------------------------
// K2: per-tile gather, scalar 1px/lane, register replay. Launch bounds relaxed
// to (256,4): VGPR cap 128 so the replay arrays (fx/fy/db/pk x 7) STAY IN
// REGISTERS -- the (.,8) cap (64 VGPR) was forcing scratch spills (rocprof
// showed VGPR_Count 16-24 with 28+ live values), and scratch L2 latency was
// the hidden serializer pinning R4-R7 at ~146 us.
// Phase A: load + decode + LDS atomicMin, capture packed geometry.
// Phase B: replay from regs, batched unconditional gate reads, masked adds.
// ---------------------------------------------------------------------------
__global__ void __launch_bounds__(TB, 4)
k2_gather(const float* __restrict__ flow, const float* __restrict__ depth,
          const int* __restrict__ nOut, const int4* __restrict__ lists,
          float* __restrict__ out) {
    __shared__ int   mind_t[TPIX];
    __shared__ float sx_t[TPIX];
    __shared__ float sy_t[TPIX];
    __shared__ float cn_t[TPIX];

    int bid = blockIdx.x;
    { const int c = NT >> 3; bid = (bid & 7) * c + (bid >> 3); }  // XCD swizzle
    const int b   = bid / TPB;
    const int tt  = bid - b * TPB;
    const int tty = tt / TILES_X;
    const int ty0 = tty * TH;
    const int tx0 = (tt - tty * TILES_X) * TW;
    const int tid = threadIdx.x;
    const float* flowb  = flow  + (size_t)b * 2 * NPIX;
    const float* depthb = depth + (size_t)b * NPIX;

    {   // vectorized init: one float4 per array per thread (TPIX == TB*4)
        int k4 = tid * 4;
        const int IB = __float_as_int(1e30f);
        *(int4*)&mind_t[k4] = make_int4(IB, IB, IB, IB);
        float4 z = make_float4(0.f, 0.f, 0.f, 0.f);
        *(float4*)&sx_t[k4] = z;
        *(float4*)&sy_t[k4] = z;
        *(float4*)&cn_t[k4] = z;
    }
    __syncthreads();

    // ---- phase A: scalar window scan, capture regs, LDS min ----
    float    fxA[NITER], fyA[NITER];
    int      dbA[NITER];
    unsigned pkA[NITER];
#pragma unroll
    for (int it = 0; it < NITER; ++it) {
        pkA[it] = 0u;
        int s  = tid + it * TB;
        int wy = s / WWIN;
        int wx = s - wy * WWIN;
        int gy = ty0 - RHALO + wy;
        int gx = tx0 - RHALO + wx;
        if (s >= WPOS || (unsigned)gy >= HH || (unsigned)gx >= WW) continue;
        int p = gy * WW + gx;
        float fx = flowb[p];
        float fy = flowb[p + NPIX];
        float d  = depthb[p];
        fxA[it] = fx; fyA[it] = fy;
        int db = __float_as_int(d);
        dbA[it] = db;
        if (!(fabsf(fx) < FMAX && fabsf(fy) < FMAX)) continue;
        float x2 = (float)gx + fx, y2 = (float)gy + fy;
        if (!(x2 >= 0.f && y2 >= 0.f && x2 <= (float)(WW - 1) && y2 <= (float)(HH - 1)))
            continue;
        int xL = (int)floorf(x2), yT = (int)floorf(y2);   // >=0 given validity
        int xR = min(xL + 1, WW - 1), yB = min(yT + 1, HH - 1);
        int cR = (xR == xL), cB = (yB == yT);
        int lxL = xL - tx0, lyT = yT - ty0;
        int lxR = lxL + (cR ^ 1), lyB = lyT + (cB ^ 1);
        pkA[it] = 0x80000000u | (unsigned)((lyT + 8) << 9) |
                  (unsigned)((lxL + 8) << 2) | (unsigned)(cR << 1) | (unsigned)cB;
        if ((unsigned)lyT < TH) {
            if ((unsigned)lxL < TW) atomicMin(&mind_t[lyT * TW + lxL], db);
            if ((unsigned)lxR < TW) atomicMin(&mind_t[lyT * TW + lxR], db);
        }
        if ((unsigned)lyB < TH) {
            if ((unsigned)lxL < TW) atomicMin(&mind_t[lyB * TW + lxL], db);
            if ((unsigned)lxR < TW) atomicMin(&mind_t[lyB * TW + lxR], db);
        }
    }
    // ---- outlier mins (per-batch list, self-contained entries) ----
    const int nb = min(nOut[b], CAPB);
    for (int j = tid; j < nb; j += TB) {
        int4 e = lists[b * CAPB + j];
        float fx = __int_as_float(e.y), fy = __int_as_float(e.z);
        int y = e.x / WW, x = e.x - y * WW;
        float x2 = (float)x + fx, y2 = (float)y + fy;
        int xL = min(max((int)floorf(x2), 0), WW - 1);
        int yT = min(max((int)floorf(y2), 0), HH - 1);
        int xR = min(xL + 1, WW - 1), yB = min(yT + 1, HH - 1);
        int lxL = xL - tx0, lxR = xR - tx0, lyT = yT - ty0, lyB = yB - ty0;
        if ((unsigned)lyT < TH) {
            if ((unsigned)lxL < TW) atomicMin(&mind_t[lyT * TW + lxL], e.w);
            if ((unsigned)lxR < TW) atomicMin(&mind_t[lyT * TW + lxR], e.w);
        }
        if ((unsigned)lyB < TH) {
            if ((unsigned)lxL < TW) atomicMin(&mind_t[lyB * TW + lxL], e.w);
            if ((unsigned)lxR < TW) atomicMin(&mind_t[lyB * TW + lxR], e.w);
        }
    }
    __syncthreads();

    // ---- phase B: replay from regs; batched gate reads, masked adds ----
#pragma unroll
    for (int it = 0; it < NITER; ++it) {
        unsigned pk = pkA[it];
        bool va = (pk >> 31) != 0u;
        int lxL = (int)((pk >> 2) & 0x7Fu) - 8;
        int lyT = (int)((pk >> 9) & 0x1Fu) - 8;
        int lxR = lxL + 1 - (int)((pk >> 1) & 1u);
        int lyB = lyT + 1 - (int)(pk & 1u);
        bool o0 = va && (unsigned)lyT < TH && (unsigned)lxL < TW;
        bool o1 = va && (unsigned)lyT < TH && (unsigned)lxR < TW;
        bool o2 = va && (unsigned)lyB < TH && (unsigned)lxL < TW;
        bool o3 = va && (unsigned)lyB < TH && (unsigned)lxR < TW;
        int i0 = o0 ? lyT * TW + lxL : 0;
        int i1 = o1 ? lyT * TW + lxR : 0;
        int i2 = o2 ? lyB * TW + lxL : 0;
        int i3 = o3 ? lyB * TW + lxR : 0;
        int v0 = mind_t[i0];          // 4 independent reads -> one wait
        int v1 = mind_t[i1];
        int v2 = mind_t[i2];
        int v3 = mind_t[i3];
        float fx = fxA[it], fy = fyA[it];
        int db = dbA[it];
        if (o0 && v0 == db) {
            atomicAdd(&sx_t[i0], -fx); atomicAdd(&sy_t[i0], -fy); atomicAdd(&cn_t[i0], 1.f);
        }
        if (o1 && v1 == db) {
            atomicAdd(&sx_t[i1], -fx); atomicAdd(&sy_t[i1], -fy); atomicAdd(&cn_t[i1], 1.f);
        }
        if (o2 && v2 == db) {
            atomicAdd(&sx_t[i2], -fx); atomicAdd(&sy_t[i2], -fy); atomicAdd(&cn_t[i2], 1.f);
        }
        if (o3 && v3 == db) {
            atomicAdd(&sx_t[i3], -fx); atomicAdd(&sy_t[i3], -fy); atomicAdd(&cn_t[i3], 1.f);
        }
    }
    // ---- outlier adds ----
    for (int j = tid; j < nb; j += TB) {
        int4 e = lists[b * CAPB + j];
        float fx = __int_as_float(e.y), fy = __int_as_float(e.z);
        int y = e.x / WW, x = e.x - y * WW;
        float x2 = (float)x + fx, y2 = (float)y + fy;
        int xL = min(max((int)floorf(x2), 0), WW - 1);
        int yT = min(max((int)floorf(y2), 0), HH - 1);
        int xR = min(xL + 1, WW - 1), yB = min(yT + 1, HH - 1);
        int lxL = xL - tx0, lxR = xR - tx0, lyT = yT - ty0, lyB = yB - ty0;
        int ls[4] = {
            ((unsigned)lyT < TH && (unsigned)lxL < TW) ? lyT * TW + lxL : -1,
            ((unsigned)lyT < TH && (unsigned)lxR < TW) ? lyT * TW + lxR : -1,
            ((unsigned)lyB < TH && (unsigned)lxL < TW) ? lyB * TW + lxL : -1,
            ((unsigned)lyB < TH && (unsigned)lxR < TW) ? lyB * TW + lxR : -1 };
#pragma unroll
        for (int c = 0; c < 4; ++c) {
            int l = ls[c];
            if (l >= 0 && mind_t[l] == e.w) {
                atomicAdd(&sx_t[l], -fx);
                atomicAdd(&sy_t[l], -fy);
                atomicAdd(&cn_t[l], 1.0f);
            }
        }
    }
    __syncthreads();

    // ---- epilogue: divide + float4 store of the owned tile ----
    {
        int k4 = tid * 4;
        int ly = k4 >> 6;          // /TW
        int lx = k4 & 63;
        float4 s4 = *(float4*)&sx_t[k4];
        float4 t4 = *(float4*)&sy_t[k4];
        float4 c4 = *(float4*)&cn_t[k4];
        float4 ox, oy;
        ox.x = (c4.x > 0.f) ? s4.x / c4.x : 0.f;  oy.x = (c4.x > 0.f) ? t4.x / c4.x : 0.f;
        ox.y = (c4.y > 0.f) ? s4.y / c4.y : 0.f;  oy.y = (c4.y > 0.f) ? t4.y / c4.y : 0.f;
        ox.z = (c4.z > 0.f) ? s4.z / c4.z : 0.f;  oy.z = (c4.z > 0.f) ? t4.z / c4.z : 0.f;
        ox.w = (c4.w > 0.f) ? s4.w / c4.w : 0.f;  oy.w = (c4.w > 0.f) ? t4.w / c4.w : 0.f;
        size_t o = (size_t)b * 2 * NPIX + (size_t)(ty0 + ly) * WW + (tx0 + lx);
        *(float4*)&out[o]        = ox;
        *(float4*)&out[o + NPIX] = oy;
    }
}

extern "C" void kernel_launch(void* const* d_in, const int* in_sizes, int n_in,
                              void* d_out, int out_size, void* d_ws, size_t ws_size,
                              hipStream_t stream) {
    const float* flow  = (const float*)d_in[0];
    const float* depth = (const float*)d_in[1];
    float* out = (float*)d_out;

    int*  nOut  = (int*)d_ws;                 // 16 ints (first NB used)
    int4* lists = (int4*)((char*)d_ws + 64);  // NB * CAPB entries

    hipMemsetAsync(nOut, 0, 64, stream);
    k1_outliers<<<TOTAL / 4 / 256, 256, 0, stream>>>(flow, depth, nOut, lists);
    k2_gather  <<<NT, TB, 0, stream>>>(flow, depth, nOut, lists, out);
}